// Round 1
// baseline (10418.362 us; speedup 1.0000x reference)
//
#include <hip/hip_runtime.h>

#define B_ 64
#define T_ 256
#define LC_ 16
#define CV_ 128
#define CE_ 100
#define WE_ 300
#define CH_ 100
#define WH_ 300
#define NTAG 20
#define START_ 18
#define STOP_ 19
#define NEG_ -10000.0f
#define NSEQ (B_*T_)          // 16384
#define GW (4*WH_)            // 1200
#define GC (4*CH_)            // 400
#define KF (WE_+CH_)          // 400

typedef unsigned short ushort_t;

__device__ inline float bf2f(ushort_t u){ return __uint_as_float(((unsigned int)u)<<16); }
__device__ inline ushort_t f2bf(float f){
  unsigned int x = __float_as_uint(f);
  unsigned int r = (x + 0x7fffu + ((x>>16)&1u)) >> 16;
  return (ushort_t)r;
}
__device__ inline float sigm(float x){ return 1.f/(1.f+__expf(-x)); }
__device__ inline float ftanh(float x){
  float ax = fabsf(x);
  float e = __expf(-2.f*ax);
  float t = (1.f-e)/(1.f+e);
  return copysignf(t, x);
}

// ---------- 1. char gate table: Ec[r][c] = char_emb[c] . cW_ih[r] + cb_ih[r]+cb_hh[r]
__global__ __launch_bounds__(256) void k_ctab(const float* __restrict__ cemb,
    const float* __restrict__ cWih, const float* __restrict__ cbih,
    const float* __restrict__ cbhh, float* __restrict__ Ec){
  int idx = blockIdx.x*256 + threadIdx.x;      // 51200 = 400*128
  int r = idx >> 7, c = idx & 127;
  float a = cbih[r] + cbhh[r];
  for (int k=0;k<CE_;++k) a += cemb[c*CE_+k]*cWih[r*CE_+k];
  Ec[r*128 + c] = a;
}

// ---------- 2. convert word W_hh (both dirs) to bf16
__global__ __launch_bounds__(256) void k_cvt(const float* __restrict__ fWhh,
    const float* __restrict__ bWhh, ushort_t* __restrict__ whh){
  int idx = blockIdx.x*256 + threadIdx.x;
  if (idx >= 2*GW*WH_) return;
  float v = (idx < GW*WH_) ? fWhh[idx] : bWhh[idx - GW*WH_];
  whh[idx] = f2bf(v);
}

// ---------- 3. char LSTM: 64 seqs per WG, wave w owns units [25w,25w+25)
__global__ __launch_bounds__(256) void k_char(const float* __restrict__ Ec,
    const float* __restrict__ Whh, const int* __restrict__ char_x,
    float* __restrict__ c_h){
  __shared__ __attribute__((aligned(16))) float h_s[64][108];
  __shared__ __attribute__((aligned(16))) float c_s[64][108];
  int tid = threadIdx.x;
  int lane = tid & 63;
  int w = __builtin_amdgcn_readfirstlane(tid >> 6);
  int seq = blockIdx.x*64 + lane;
  float* hs = &h_s[0][0]; float* cs = &c_s[0][0];
  for (int i=tid; i<64*108; i+=256){ hs[i]=0.f; cs[i]=0.f; }
  __syncthreads();
  const int* cx = char_x + (size_t)seq*LC_;
  #pragma unroll 1
  for (int t=0; t<LC_; ++t){
    float hr[100];
    #pragma unroll
    for (int q=0;q<25;++q){
      float4 v = *(const float4*)&h_s[lane][q*4];
      hr[q*4]=v.x; hr[q*4+1]=v.y; hr[q*4+2]=v.z; hr[q*4+3]=v.w;
    }
    int ch = cx[t];
    __syncthreads();           // everyone done reading old h
    #pragma unroll 1
    for (int jj=0;jj<25;++jj){
      int j = w*25 + jj;
      float ai = Ec[(j       )*128 + ch];
      float af = Ec[(100 + j )*128 + ch];
      float ag = Ec[(200 + j )*128 + ch];
      float ao = Ec[(300 + j )*128 + ch];
      const float* wi = Whh + (size_t)(j      )*CE_;
      const float* wf = Whh + (size_t)(100 + j)*CE_;
      const float* wg = Whh + (size_t)(200 + j)*CE_;
      const float* wo = Whh + (size_t)(300 + j)*CE_;
      #pragma unroll
      for (int k=0;k<100;++k){
        float hk = hr[k];
        ai += wi[k]*hk; af += wf[k]*hk; ag += wg[k]*hk; ao += wo[k]*hk;
      }
      float I = sigm(ai), F = sigm(af), G = ftanh(ag), O = sigm(ao);
      float cn = F*c_s[lane][j] + I*G;
      float hn = O*ftanh(cn);
      if (ch > 0){ c_s[lane][j] = cn; h_s[lane][j] = hn; }
    }
    __syncthreads();           // writes visible for next step
  }
  #pragma unroll 1
  for (int jj=0;jj<25;++jj){ int j=w*25+jj; c_h[(size_t)seq*CH_+j] = h_s[lane][j]; }
}

// ---------- 4. xg GEMM: xg[dir][n][r] = feat[n] . W_ih_dir[r]   (feat gathered on the fly)
__global__ __launch_bounds__(256) void k_xg(const int* __restrict__ word_x,
    const float* __restrict__ wemb, const float* __restrict__ c_h,
    const float* __restrict__ fW, const float* __restrict__ bW,
    ushort_t* __restrict__ xg){
  __shared__ __attribute__((aligned(16))) ushort_t A_s[64][20];
  __shared__ __attribute__((aligned(16))) float    B_s[16][68];
  int tid = threadIdx.x;
  int m0 = blockIdx.x*64, n0 = blockIdx.y*64, dir = blockIdx.z;
  const float* W = dir ? bW : fW;
  ushort_t* out = xg + (size_t)dir*NSEQ*GW;
  int tx = tid & 15, ty = tid >> 4;
  int mm = tid >> 2, ks4 = (tid & 3)*4;
  float acc[4][4] = {};
  #pragma unroll 1
  for (int kc=0; kc<25; ++kc){
    int k0 = kc*16;
    {
      int m = m0 + mm;
      int k = k0 + ks4;
      float4 v;
      if (k < WE_){ int wid = word_x[m]; v = *(const float4*)&wemb[(size_t)wid*WE_ + k]; }
      else        { v = *(const float4*)&c_h[(size_t)m*CH_ + (k - WE_)]; }
      ushort4 u; u.x=f2bf(v.x); u.y=f2bf(v.y); u.z=f2bf(v.z); u.w=f2bf(v.w);
      *(ushort4*)&A_s[mm][ks4] = u;
    }
    {
      int r = n0 + mm;
      float4 wv = make_float4(0.f,0.f,0.f,0.f);
      if (r < GW) wv = *(const float4*)&W[(size_t)r*KF + k0 + ks4];
      B_s[ks4+0][mm]=wv.x; B_s[ks4+1][mm]=wv.y; B_s[ks4+2][mm]=wv.z; B_s[ks4+3][mm]=wv.w;
    }
    __syncthreads();
    #pragma unroll
    for (int kp=0; kp<8; ++kp){
      float a0[4], a1[4];
      #pragma unroll
      for (int i=0;i<4;++i){
        unsigned int u = *(const unsigned int*)&A_s[ty*4+i][kp*2];
        a0[i] = __uint_as_float(u<<16);
        a1[i] = __uint_as_float(u & 0xffff0000u);
      }
      float4 b0 = *(const float4*)&B_s[kp*2  ][tx*4];
      float4 b1 = *(const float4*)&B_s[kp*2+1][tx*4];
      #pragma unroll
      for (int i=0;i<4;++i){
        acc[i][0] += a0[i]*b0.x + a1[i]*b1.x;
        acc[i][1] += a0[i]*b0.y + a1[i]*b1.y;
        acc[i][2] += a0[i]*b0.z + a1[i]*b1.z;
        acc[i][3] += a0[i]*b0.w + a1[i]*b1.w;
      }
    }
    __syncthreads();
  }
  #pragma unroll
  for (int i=0;i<4;++i){
    int m = m0 + ty*4 + i;
    #pragma unroll
    for (int j=0;j<4;++j){
      int r = n0 + tx*4 + j;
      if (r < GW) out[(size_t)m*GW + r] = f2bf(acc[i][j]);
    }
  }
}

// ---------- 5. word LSTM (one WG per batch x direction; also projects logits per step)
__global__ __launch_bounds__(256) void k_word(const ushort_t* __restrict__ xg,
    const ushort_t* __restrict__ whh,
    const float* __restrict__ fbih, const float* __restrict__ fbhh,
    const float* __restrict__ bbih, const float* __restrict__ bbhh,
    const int* __restrict__ word_x, const float* __restrict__ outW,
    float* __restrict__ logits){
  __shared__ __attribute__((aligned(16))) float h_s[304];
  __shared__ __attribute__((aligned(16))) float c_s[304];
  __shared__ float g_s[GW];
  int tid = threadIdx.x;
  int dir = blockIdx.x & 1, b = blockIdx.x >> 1;
  const ushort_t* W = whh + (size_t)dir*GW*WH_;
  const ushort_t* X = xg  + (size_t)dir*NSEQ*GW + (size_t)b*T_*GW;
  const float* bi = dir ? bbih : fbih;
  const float* bh = dir ? bbhh : fbhh;
  float bias[5];
  #pragma unroll
  for (int i=0;i<5;++i){ int r = tid + 256*i; bias[i] = (r<GW) ? (bi[r]+bh[r]) : 0.f; }
  for (int j=tid; j<304; j+=256){ h_s[j]=0.f; c_s[j]=0.f; }
  __syncthreads();
  float* lg = logits + (size_t)dir*NSEQ*NTAG + (size_t)b*T_*NTAG;
  #pragma unroll 1
  for (int s=0; s<T_; ++s){
    int t = dir ? (T_-1-s) : s;
    float acc[5];
    #pragma unroll
    for (int i=0;i<5;++i){
      int r = tid + 256*i;
      acc[i] = (r<GW) ? (bias[i] + bf2f(X[(size_t)t*GW + r])) : 0.f;
    }
    #pragma unroll 1
    for (int kc=0; kc<5; ++kc){
      float hr[60];
      #pragma unroll
      for (int q=0;q<15;++q){
        float4 v = *(const float4*)&h_s[kc*60 + q*4];
        hr[q*4]=v.x; hr[q*4+1]=v.y; hr[q*4+2]=v.z; hr[q*4+3]=v.w;
      }
      #pragma unroll
      for (int i=0;i<5;++i){
        int r = tid + 256*i;
        if (r < GW){
          const ushort4* wp = (const ushort4*)(W + (size_t)r*WH_ + kc*60);
          float a = acc[i];
          #pragma unroll
          for (int q=0;q<15;++q){
            ushort4 w4 = wp[q];
            a += bf2f(w4.x)*hr[q*4] + bf2f(w4.y)*hr[q*4+1]
               + bf2f(w4.z)*hr[q*4+2] + bf2f(w4.w)*hr[q*4+3];
          }
          acc[i] = a;
        }
      }
    }
    #pragma unroll
    for (int i=0;i<5;++i){ int r = tid + 256*i; if (r<GW) g_s[r] = acc[i]; }
    __syncthreads();
    int m_t = word_x[b*T_ + t] > 0;
    if (tid < WH_){
      float I = sigm(g_s[tid]);
      float F = sigm(g_s[WH_ + tid]);
      float G = ftanh(g_s[2*WH_ + tid]);
      float O = sigm(g_s[3*WH_ + tid]);
      float cn = F*c_s[tid] + I*G;
      float hn = O*ftanh(cn);
      if (m_t){ c_s[tid] = cn; h_s[tid] = hn; }
    }
    __syncthreads();
    if (tid < 160){
      int i = tid >> 3, o = tid & 7;
      const float* wrow = outW + i*(2*WH_) + dir*WH_;
      float p = 0.f;
      for (int k=o; k<WH_; k+=8) p += h_s[k]*wrow[k];
      p += __shfl_down(p, 4, 8);
      p += __shfl_down(p, 2, 8);
      p += __shfl_down(p, 1, 8);
      if (o == 0) lg[t*NTAG + i] = p;
    }
    __syncthreads();
  }
}

// ---------- 6. CRF forward + gold score (one wave per batch element)
__global__ __launch_bounds__(64) void k_crf(const float* __restrict__ logits,
    const float* __restrict__ out_b, const float* __restrict__ tr,
    const int* __restrict__ word_x, const int* __restrict__ y,
    float* __restrict__ out){
  __shared__ float tr_s[NTAG][21];
  __shared__ float al[NTAG];
  __shared__ float tmp[NTAG];
  int b = blockIdx.x, lane = threadIdx.x;
  for (int idx=lane; idx<NTAG*NTAG; idx+=64) tr_s[idx/NTAG][idx%NTAG] = tr[idx];
  if (lane < NTAG) al[lane] = (lane == START_) ? 0.f : NEG_;
  __syncthreads();
  const float* lf = logits + (size_t)b*T_*NTAG;
  const float* lb = logits + (size_t)NSEQ*NTAG + (size_t)b*T_*NTAG;
  #pragma unroll 1
  for (int t=0; t<T_; ++t){
    float anew = 0.f;
    int m_t = word_x[b*T_ + t] > 0;
    if (lane < NTAG){
      float hv = lf[t*NTAG + lane] + lb[t*NTAG + lane] + out_b[lane];
      float mx = -3.4e38f;
      #pragma unroll
      for (int j=0;j<NTAG;++j) mx = fmaxf(mx, al[j] + tr_s[lane][j]);
      float ss = 0.f;
      #pragma unroll
      for (int j=0;j<NTAG;++j) ss += __expf(al[j] + tr_s[lane][j] - mx);
      anew = __logf(ss) + mx + hv;
      if (!m_t) anew = al[lane];
    }
    __syncthreads();
    if (lane < NTAG) al[lane] = anew;
    __syncthreads();
  }
  if (lane < NTAG) tmp[lane] = al[lane] + tr_s[STOP_][lane];
  __syncthreads();
  float sc = 0.f; int cnt = 0;
  #pragma unroll 1
  for (int q=0;q<4;++q){
    int t = lane + 64*q;
    if (word_x[b*T_ + t] > 0){
      int yt = y[b*T_ + t];
      int yp = (t == 0) ? START_ : y[b*T_ + t - 1];
      sc += lf[t*NTAG + yt] + lb[t*NTAG + yt] + out_b[yt] + tr_s[yt][yp];
      cnt++;
    }
  }
  for (int off=32; off; off>>=1){
    sc += __shfl_down(sc, off);
    cnt += __shfl_down(cnt, off);
  }
  if (lane == 0){
    float mx = -3.4e38f;
    for (int j=0;j<NTAG;++j) mx = fmaxf(mx, tmp[j]);
    float ss = 0.f;
    for (int j=0;j<NTAG;++j) ss += __expf(tmp[j] - mx);
    float Z = __logf(ss) + mx;
    int last = y[b*T_ + cnt - 1];
    sc += tr_s[STOP_][last];
    out[b] = Z - sc;
  }
}

extern "C" void kernel_launch(void* const* d_in, const int* in_sizes, int n_in,
                              void* d_out, int out_size, void* d_ws, size_t ws_size,
                              hipStream_t stream) {
  (void)in_sizes; (void)n_in; (void)out_size; (void)ws_size;
  const int*   word_x  = (const int*)  d_in[0];
  const int*   char_x  = (const int*)  d_in[1];
  const int*   y       = (const int*)  d_in[2];
  const float* wemb    = (const float*)d_in[3];
  const float* cemb    = (const float*)d_in[4];
  const float* cWih    = (const float*)d_in[5];
  const float* cWhh    = (const float*)d_in[6];
  const float* cbih    = (const float*)d_in[7];
  const float* cbhh    = (const float*)d_in[8];
  const float* fWih    = (const float*)d_in[9];
  const float* fWhh    = (const float*)d_in[10];
  const float* fbih    = (const float*)d_in[11];
  const float* fbhh    = (const float*)d_in[12];
  const float* bWih    = (const float*)d_in[13];
  const float* bWhh    = (const float*)d_in[14];
  const float* bbih    = (const float*)d_in[15];
  const float* bbhh    = (const float*)d_in[16];
  const float* outW    = (const float*)d_in[17];
  const float* outb    = (const float*)d_in[18];
  const float* trans   = (const float*)d_in[19];
  float* out = (float*)d_out;

  char* ws = (char*)d_ws;
  float*    Ec     = (float*)   (ws + 0);                    // 400*128 f32      = 204800 B
  ushort_t* whh    = (ushort_t*)(ws + 204800);               // 2*1200*300 bf16  = 1440000 B
  float*    c_h    = (float*)   (ws + 1644800);              // 16384*100 f32    = 6553600 B
  ushort_t* xg     = (ushort_t*)(ws + 8198400);              // 2*16384*1200 bf16= 78643200 B
  float*    logits = (float*)   (ws + 86841600);             // 2*16384*20 f32   = 2621440 B
                                                             // total 89463040 B

  hipLaunchKernelGGL(k_ctab, dim3(200), dim3(256), 0, stream, cemb, cWih, cbih, cbhh, Ec);
  hipLaunchKernelGGL(k_cvt,  dim3((2*GW*WH_ + 255)/256), dim3(256), 0, stream, fWhh, bWhh, whh);
  hipLaunchKernelGGL(k_char, dim3(256), dim3(256), 0, stream, Ec, cWhh, char_x, c_h);
  hipLaunchKernelGGL(k_xg,   dim3(256, 19, 2), dim3(256), 0, stream, word_x, wemb, c_h, fWih, bWih, xg);
  hipLaunchKernelGGL(k_word, dim3(128), dim3(256), 0, stream, xg, whh, fbih, fbhh, bbih, bbhh, word_x, outW, logits);
  hipLaunchKernelGGL(k_crf,  dim3(64), dim3(64), 0, stream, logits, outb, trans, word_x, y, out);
}

// Round 4
// 5256.073 us; speedup vs baseline: 1.9822x; 1.9822x over previous
//
#include <hip/hip_runtime.h>

#define B_ 64
#define T_ 256
#define LC_ 16
#define CV_ 128
#define CE_ 100
#define WE_ 300
#define CH_ 100
#define WH_ 300
#define NTAG 20
#define START_ 18
#define STOP_ 19
#define NEG_ -10000.0f
#define NSEQ (B_*T_)          // 16384
#define GW (4*WH_)            // 1200
#define KF (WE_+CH_)          // 400
#define NW_ 25                // workgroups per direction in k_word2
#define UH_ 12                // hidden units per workgroup (25*12=300)

typedef unsigned short ushort_t;
typedef __attribute__((ext_vector_type(8))) short bf16x8;
typedef __attribute__((ext_vector_type(4))) float f32x4;
union BF8 { bf16x8 v; ushort_t u[8]; };

__device__ inline float bf2f(ushort_t u){ return __uint_as_float(((unsigned int)u)<<16); }
__device__ inline ushort_t f2bf(float f){
  unsigned int x = __float_as_uint(f);
  unsigned int r = (x + 0x7fffu + ((x>>16)&1u)) >> 16;
  return (ushort_t)r;
}
__device__ inline float sigm(float x){ return 1.f/(1.f+__expf(-x)); }
__device__ inline float ftanh(float x){
  float ax = fabsf(x);
  float e = __expf(-2.f*ax);
  float t = (1.f-e)/(1.f+e);
  return copysignf(t, x);
}

// ---------- 0. init: zero h-history (incl. padding cols) and sync counters
#define HH_SHORTS (2*257*64*304)   // 10,000,384 shorts = 20,000,768 bytes
#define HH_DWORDS (HH_SHORTS/2)
__global__ __launch_bounds__(256) void k_init(unsigned int* __restrict__ hh, int* __restrict__ cnt){
  size_t idx = (size_t)blockIdx.x*256 + threadIdx.x;
  if (idx < HH_DWORDS) hh[idx] = 0u;
  else if (idx < HH_DWORDS + 32) cnt[idx - HH_DWORDS] = 0;
}

// ---------- 1. char gate table: Ec[r][c] = char_emb[c] . cW_ih[r] + cb_ih[r]+cb_hh[r]
__global__ __launch_bounds__(256) void k_ctab(const float* __restrict__ cemb,
    const float* __restrict__ cWih, const float* __restrict__ cbih,
    const float* __restrict__ cbhh, float* __restrict__ Ec){
  int idx = blockIdx.x*256 + threadIdx.x;      // 51200 = 400*128
  int r = idx >> 7, c = idx & 127;
  float a = cbih[r] + cbhh[r];
  for (int k=0;k<CE_;++k) a += cemb[c*CE_+k]*cWih[r*CE_+k];
  Ec[r*128 + c] = a;
}

// ---------- 2. char LSTM: 64 seqs per WG, wave w owns units [25w,25w+25)
__global__ __launch_bounds__(256) void k_char(const float* __restrict__ Ec,
    const float* __restrict__ Whh, const int* __restrict__ char_x,
    float* __restrict__ c_h){
  __shared__ __attribute__((aligned(16))) float h_s[64][108];
  __shared__ __attribute__((aligned(16))) float c_s[64][108];
  int tid = threadIdx.x;
  int lane = tid & 63;
  int w = __builtin_amdgcn_readfirstlane(tid >> 6);
  int seq = blockIdx.x*64 + lane;
  float* hs = &h_s[0][0]; float* cs = &c_s[0][0];
  for (int i=tid; i<64*108; i+=256){ hs[i]=0.f; cs[i]=0.f; }
  __syncthreads();
  const int* cx = char_x + (size_t)seq*LC_;
  #pragma unroll 1
  for (int t=0; t<LC_; ++t){
    float hr[100];
    #pragma unroll
    for (int q=0;q<25;++q){
      float4 v = *(const float4*)&h_s[lane][q*4];
      hr[q*4]=v.x; hr[q*4+1]=v.y; hr[q*4+2]=v.z; hr[q*4+3]=v.w;
    }
    int ch = cx[t];
    __syncthreads();
    #pragma unroll 1
    for (int jj=0;jj<25;++jj){
      int j = w*25 + jj;
      float ai = Ec[(j       )*128 + ch];
      float af = Ec[(100 + j )*128 + ch];
      float ag = Ec[(200 + j )*128 + ch];
      float ao = Ec[(300 + j )*128 + ch];
      const float* wi = Whh + (size_t)(j      )*CE_;
      const float* wf = Whh + (size_t)(100 + j)*CE_;
      const float* wg = Whh + (size_t)(200 + j)*CE_;
      const float* wo = Whh + (size_t)(300 + j)*CE_;
      #pragma unroll
      for (int k=0;k<100;++k){
        float hk = hr[k];
        ai += wi[k]*hk; af += wf[k]*hk; ag += wg[k]*hk; ao += wo[k]*hk;
      }
      float I = sigm(ai), F = sigm(af), G = ftanh(ag), O = sigm(ao);
      float cn = F*c_s[lane][j] + I*G;
      float hn = O*ftanh(cn);
      if (ch > 0){ c_s[lane][j] = cn; h_s[lane][j] = hn; }
    }
    __syncthreads();
  }
  #pragma unroll 1
  for (int jj=0;jj<25;++jj){ int j=w*25+jj; c_h[(size_t)seq*CH_+j] = h_s[lane][j]; }
}

// ---------- 3. feat builder: feat[t][b][0..400) bf16 = concat(wemb[word_x], c_h)
__global__ __launch_bounds__(256) void k_feat(const int* __restrict__ word_x,
    const float* __restrict__ wemb, const float* __restrict__ c_h,
    ushort_t* __restrict__ feat){
  int gid = blockIdx.x*256 + threadIdx.x;      // 16384*100 groups of 4 cols
  int rf = gid / 100;                          // rf = t*64 + b
  int j4 = gid - rf*100;
  int k = 4*j4;
  int t = rf >> 6, b = rf & 63;
  int seq = b*T_ + t;
  float4 v;
  if (k < WE_){ int wid = word_x[seq]; v = *(const float4*)&wemb[(size_t)wid*WE_ + k]; }
  else        { v = *(const float4*)&c_h[(size_t)seq*CH_ + (k - WE_)]; }
  ushort4 u; u.x=f2bf(v.x); u.y=f2bf(v.y); u.z=f2bf(v.z); u.w=f2bf(v.w);
  *(ushort4*)&feat[(size_t)rf*KF + k] = u;
}

// ---------- 4. word LSTM: distributed recurrence, persistent weights in VGPRs,
//              MFMA gates, spin-barrier across NW_ WGs per direction.
__global__ __launch_bounds__(512, 2) void k_word2(
    const ushort_t* __restrict__ feat, ushort_t* __restrict__ hh,
    const float* __restrict__ fWih, const float* __restrict__ fWhh,
    const float* __restrict__ fbih, const float* __restrict__ fbhh,
    const float* __restrict__ bWih, const float* __restrict__ bWhh,
    const float* __restrict__ bbih, const float* __restrict__ bbhh,
    const int* __restrict__ word_x, int* __restrict__ cnt){
  extern __shared__ char smem[];
  ushort_t* h_s = (ushort_t*)smem;                         // [64][328] bf16 = 41984 B
  ushort_t* f_s = (ushort_t*)(smem + 64*328*2);            // [64][416] bf16 = 53248 B
  float*    g_s = (float*)   (smem + 64*328*2 + 64*416*2); // [64][52] f32   = 13312 B
  const int tid  = threadIdx.x;
  const int lane = tid & 63;
  const int w    = tid >> 6;         // 8 waves
  const int dir  = blockIdx.x & 1;
  const int g    = blockIdx.x >> 1;  // 0..24
  const int u0   = g * UH_;
  const int tm   = w & 3;            // m-tile (batch 16-row group)
  const int grp  = w >> 2;           // 0: n-tiles {0,1}; 1: n-tile {2}
  const bool two = (grp == 0);
  const int tnb  = grp ? 2 : 0;
  const float* Wih = dir ? bWih : fWih;
  const float* Whh = dir ? bWhh : fWhh;
  const float* bi  = dir ? bbih : fbih;
  const float* bh  = dir ? bbhh : fbhh;
  int* mycnt = cnt + dir*16;

  // ---- persistent B fragments (W_ih: 13 k-slabs; W_hh: 10 k-slabs)
  bf16x8 B2[2][13], B1[2][10];
  {
    const int kb = 8*(lane >> 4);
    #pragma unroll
    for (int ti=0; ti<2; ++ti){
      if (ti == 0 || two){
        int nl = 16*(tnb+ti) + (lane & 15);
        int r  = (nl & 3)*WH_ + u0 + (nl >> 2);   // gate q*300 + unit
        #pragma unroll
        for (int kk=0; kk<13; ++kk){
          BF8 tmp;
          #pragma unroll
          for (int j=0; j<8; ++j){
            int k = 32*kk + kb + j;
            tmp.u[j] = (k < KF) ? f2bf(Wih[(size_t)r*KF + k]) : (ushort_t)0;
          }
          B2[ti][kk] = tmp.v;
        }
        #pragma unroll
        for (int kk=0; kk<10; ++kk){
          BF8 tmp;
          #pragma unroll
          for (int j=0; j<8; ++j){
            int k = 32*kk + kb + j;
            tmp.u[j] = (k < WH_) ? f2bf(Whh[(size_t)r*WH_ + k]) : (ushort_t)0;
          }
          B1[ti][kk] = tmp.v;
        }
      }
    }
  }
  // ---- zero LDS K-padding (h cols 304..327, feat cols 400..415)
  for (int idx=tid; idx<64*24; idx+=512){ int m = idx/24; h_s[m*328 + 304 + (idx - m*24)] = 0; }
  for (int idx=tid; idx<64*16; idx+=512){ f_s[(idx>>4)*416 + 400 + (idx & 15)] = 0; }

  // ---- per-thread update state: pair A = (m_u, ula), pair B = (m_u, 8+ula) for tid<256
  const int m_u = tid & 63;
  const int ula = tid >> 6;          // 0..7
  float4 bias_a, bias_b = {0,0,0,0};
  {
    int u = u0 + ula;
    bias_a.x = bi[0*WH_+u] + bh[0*WH_+u];
    bias_a.y = bi[1*WH_+u] + bh[1*WH_+u];
    bias_a.z = bi[2*WH_+u] + bh[2*WH_+u];
    bias_a.w = bi[3*WH_+u] + bh[3*WH_+u];
    if (tid < 256){
      int ub = u0 + 8 + ula;
      bias_b.x = bi[0*WH_+ub] + bh[0*WH_+ub];
      bias_b.y = bi[1*WH_+ub] + bh[1*WH_+ub];
      bias_b.z = bi[2*WH_+ub] + bh[2*WH_+ub];
      bias_b.w = bi[3*WH_+ub] + bh[3*WH_+ub];
    }
  }
  float c_a=0.f, h_a=0.f, c_b=0.f, h_b=0.f;
  const int arow_f = (16*tm + (lane&15))*416 + 8*(lane>>4);
  const int arow_h = (16*tm + (lane&15))*328 + 8*(lane>>4);
  __syncthreads();

  #pragma unroll 1
  for (int s=0; s<T_; ++s){
    int t = dir ? (T_-1-s) : s;
    // -- wait until all WGs of this dir published h slot s
    if (s > 0 && tid == 0){
      int tgt = NW_*s;
      for (int it=0; it<1000000; ++it){
        if (__hip_atomic_load(mycnt, __ATOMIC_RELAXED, __HIP_MEMORY_SCOPE_AGENT) >= tgt) break;
        __builtin_amdgcn_s_sleep(1);
      }
      __builtin_amdgcn_fence(__ATOMIC_ACQUIRE, "agent");
    }
    __syncthreads();
    // -- stage h(s): 64 rows x 304 bf16
    {
      const ushort_t* hsrc = hh + ((size_t)(dir*257 + s)*64)*304;
      for (int idx=tid; idx<2432; idx+=512){
        int m = idx/38, j = idx - m*38;
        uint4 v = *(const uint4*)(hsrc + m*304 + 8*j);
        *(uint4*)(h_s + m*328 + 8*j) = v;
      }
    }
    // -- stage feat(t): 64 rows x 400 bf16
    {
      const ushort_t* fsrc = feat + (size_t)t*64*KF;
      for (int idx=tid; idx<3200; idx+=512){
        int m = idx/50, j = idx - m*50;
        uint4 v = *(const uint4*)(fsrc + m*KF + 8*j);
        *(uint4*)(f_s + m*416 + 8*j) = v;
      }
    }
    __syncthreads();
    // -- MFMA: gates(64 x 48-slice) = feat*Wih^T + h*Whh^T
    f32x4 acc0a = {0,0,0,0}, acc0b = {0,0,0,0}, acc1a = {0,0,0,0}, acc1b = {0,0,0,0};
    #pragma unroll
    for (int kk=0; kk<13; ++kk){
      bf16x8 a = *(const bf16x8*)(f_s + arow_f + 32*kk);
      if (kk & 1){
        acc0b = __builtin_amdgcn_mfma_f32_16x16x32_bf16(a, B2[0][kk], acc0b, 0,0,0);
        if (two) acc1b = __builtin_amdgcn_mfma_f32_16x16x32_bf16(a, B2[1][kk], acc1b, 0,0,0);
      } else {
        acc0a = __builtin_amdgcn_mfma_f32_16x16x32_bf16(a, B2[0][kk], acc0a, 0,0,0);
        if (two) acc1a = __builtin_amdgcn_mfma_f32_16x16x32_bf16(a, B2[1][kk], acc1a, 0,0,0);
      }
    }
    #pragma unroll
    for (int kk=0; kk<10; ++kk){
      bf16x8 a = *(const bf16x8*)(h_s + arow_h + 32*kk);
      if (kk & 1){
        acc0b = __builtin_amdgcn_mfma_f32_16x16x32_bf16(a, B1[0][kk], acc0b, 0,0,0);
        if (two) acc1b = __builtin_amdgcn_mfma_f32_16x16x32_bf16(a, B1[1][kk], acc1b, 0,0,0);
      } else {
        acc0a = __builtin_amdgcn_mfma_f32_16x16x32_bf16(a, B1[0][kk], acc0a, 0,0,0);
        if (two) acc1a = __builtin_amdgcn_mfma_f32_16x16x32_bf16(a, B1[1][kk], acc1a, 0,0,0);
      }
    }
    __syncthreads();
    {
      int nb = 16*tnb + (lane & 15);
      int mr = 16*tm + 4*(lane >> 4);
      f32x4 s0 = acc0a + acc0b;
      #pragma unroll
      for (int r4=0; r4<4; ++r4) g_s[(mr+r4)*52 + nb] = s0[r4];
      if (two){
        f32x4 s1 = acc1a + acc1b;
        #pragma unroll
        for (int r4=0; r4<4; ++r4) g_s[(mr+r4)*52 + nb + 16] = s1[r4];
      }
    }
    __syncthreads();
    // -- elementwise LSTM update + publish carried h (bf16)
    {
      int mt = word_x[m_u*T_ + t] > 0;
      ushort_t* hdst = hh + ((size_t)(dir*257 + s + 1)*64 + m_u)*304;
      {
        float4 ga = *(const float4*)(g_s + m_u*52 + 4*ula);
        float gi = sigm (ga.x + bias_a.x);
        float gf = sigm (ga.y + bias_a.y);
        float gg = ftanh(ga.z + bias_a.z);
        float go = sigm (ga.w + bias_a.w);
        float cn = gf*c_a + gi*gg;
        float hn = go*ftanh(cn);
        if (mt){ c_a = cn; h_a = hn; }
        hdst[u0 + ula] = f2bf(h_a);
      }
      if (tid < 256){
        float4 gb = *(const float4*)(g_s + m_u*52 + 4*(8+ula));
        float gi = sigm (gb.x + bias_b.x);
        float gf = sigm (gb.y + bias_b.y);
        float gg = ftanh(gb.z + bias_b.z);
        float go = sigm (gb.w + bias_b.w);
        float cn = gf*c_b + gi*gg;
        float hn = go*ftanh(cn);
        if (mt){ c_b = cn; h_b = hn; }
        hdst[u0 + 8 + ula] = f2bf(h_b);
      }
    }
    __builtin_amdgcn_fence(__ATOMIC_RELEASE, "agent");
    __syncthreads();
    if (tid == 0) __hip_atomic_fetch_add(mycnt, 1, __ATOMIC_RELAXED, __HIP_MEMORY_SCOPE_AGENT);
  }
}

// ---------- 5. logits: logits[dir][seq][tag] = h_dir(t) . outW[tag][dir*300..]
__global__ __launch_bounds__(320) void k_logits(const ushort_t* __restrict__ hh,
    const float* __restrict__ outW, float* __restrict__ logits){
  __shared__ __attribute__((aligned(16))) ushort_t h_l[16][304];
  __shared__ __attribute__((aligned(16))) float    w_l[20][304];
  int tid = threadIdx.x;
  int dir = blockIdx.y;
  for (int idx=tid; idx<20*304; idx+=320){
    int tag = idx/304, k = idx - tag*304;
    w_l[tag][k] = (k < WH_) ? outW[(size_t)tag*(2*WH_) + dir*WH_ + k] : 0.f;
  }
  for (int idx=tid; idx<608; idx+=320){
    int m = idx/38, j = idx - m*38;
    int seq = blockIdx.x*16 + m;
    int b = seq >> 8, t = seq & 255;
    int slot = dir ? (T_ - t) : (t + 1);
    uint4 v = *(const uint4*)(hh + ((size_t)(dir*257 + slot)*64 + b)*304 + 8*j);
    *(uint4*)(&h_l[m][8*j]) = v;
  }
  __syncthreads();
  int sq = tid/20, tag = tid - sq*20;
  float acc = 0.f;
  #pragma unroll
  for (int jj=0; jj<76; ++jj){
    ushort_t h0 = h_l[sq][4*jj+0], h1 = h_l[sq][4*jj+1];
    ushort_t h2 = h_l[sq][4*jj+2], h3 = h_l[sq][4*jj+3];
    float4 wv = *(const float4*)&w_l[tag][4*jj];
    acc += bf2f(h0)*wv.x + bf2f(h1)*wv.y + bf2f(h2)*wv.z + bf2f(h3)*wv.w;
  }
  int seq = blockIdx.x*16 + sq;
  logits[((size_t)dir*NSEQ + seq)*NTAG + tag] = acc;
}

// ---------- 6. CRF forward + gold score (one wave per batch element)
__global__ __launch_bounds__(64) void k_crf(const float* __restrict__ logits,
    const float* __restrict__ out_b, const float* __restrict__ tr,
    const int* __restrict__ word_x, const int* __restrict__ y,
    float* __restrict__ out){
  __shared__ float tr_s[NTAG][21];
  __shared__ float al[NTAG];
  __shared__ float tmp[NTAG];
  int b = blockIdx.x, lane = threadIdx.x;
  for (int idx=lane; idx<NTAG*NTAG; idx+=64) tr_s[idx/NTAG][idx%NTAG] = tr[idx];
  if (lane < NTAG) al[lane] = (lane == START_) ? 0.f : NEG_;
  __syncthreads();
  const float* lf = logits + (size_t)b*T_*NTAG;
  const float* lb = logits + (size_t)NSEQ*NTAG + (size_t)b*T_*NTAG;
  #pragma unroll 1
  for (int t=0; t<T_; ++t){
    float anew = 0.f;
    int m_t = word_x[b*T_ + t] > 0;
    if (lane < NTAG){
      float hv = lf[t*NTAG + lane] + lb[t*NTAG + lane] + out_b[lane];
      hv = fminf(fmaxf(hv, -1e6f), 1e6f);   // guard: legit |hv| <~ 50; catches garbage
      float mx = -3.4e38f;
      #pragma unroll
      for (int j=0;j<NTAG;++j) mx = fmaxf(mx, al[j] + tr_s[lane][j]);
      float ss = 0.f;
      #pragma unroll
      for (int j=0;j<NTAG;++j) ss += __expf(al[j] + tr_s[lane][j] - mx);
      anew = __logf(ss) + mx + hv;
      if (!m_t) anew = al[lane];
    }
    __syncthreads();
    if (lane < NTAG) al[lane] = anew;
    __syncthreads();
  }
  if (lane < NTAG) tmp[lane] = al[lane] + tr_s[STOP_][lane];
  __syncthreads();
  float sc = 0.f; int cnt = 0;
  #pragma unroll 1
  for (int q=0;q<4;++q){
    int t = lane + 64*q;
    if (word_x[b*T_ + t] > 0){
      int yt = y[b*T_ + t];
      int yp = (t == 0) ? START_ : y[b*T_ + t - 1];
      float ev = lf[t*NTAG + yt] + lb[t*NTAG + yt] + out_b[yt];
      ev = fminf(fmaxf(ev, -1e6f), 1e6f);
      sc += ev + tr_s[yt][yp];
      cnt++;
    }
  }
  for (int off=32; off; off>>=1){
    sc += __shfl_down(sc, off);
    cnt += __shfl_down(cnt, off);
  }
  if (lane == 0){
    float mx = -3.4e38f;
    for (int j=0;j<NTAG;++j) mx = fmaxf(mx, tmp[j]);
    float ss = 0.f;
    for (int j=0;j<NTAG;++j) ss += __expf(tmp[j] - mx);
    float Z = __logf(ss) + mx;
    int last = y[b*T_ + cnt - 1];
    sc += tr_s[STOP_][last];
    out[b] = Z - sc;
  }
}

extern "C" void kernel_launch(void* const* d_in, const int* in_sizes, int n_in,
                              void* d_out, int out_size, void* d_ws, size_t ws_size,
                              hipStream_t stream) {
  (void)in_sizes; (void)n_in; (void)out_size; (void)ws_size;
  const int*   word_x  = (const int*)  d_in[0];
  const int*   char_x  = (const int*)  d_in[1];
  const int*   y       = (const int*)  d_in[2];
  const float* wemb    = (const float*)d_in[3];
  const float* cemb    = (const float*)d_in[4];
  const float* cWih    = (const float*)d_in[5];
  const float* cWhh    = (const float*)d_in[6];
  const float* cbih    = (const float*)d_in[7];
  const float* cbhh    = (const float*)d_in[8];
  const float* fWih    = (const float*)d_in[9];
  const float* fWhh    = (const float*)d_in[10];
  const float* fbih    = (const float*)d_in[11];
  const float* fbhh    = (const float*)d_in[12];
  const float* bWih    = (const float*)d_in[13];
  const float* bWhh    = (const float*)d_in[14];
  const float* bbih    = (const float*)d_in[15];
  const float* bbhh    = (const float*)d_in[16];
  const float* outW    = (const float*)d_in[17];
  const float* outb    = (const float*)d_in[18];
  const float* trans   = (const float*)d_in[19];
  float* out = (float*)d_out;

  char* ws = (char*)d_ws;
  // layout (bytes, 16-aligned):
  float*    Ec     = (float*)   (ws + 0);          //   204,800
  float*    c_h    = (float*)   (ws + 204800);     // 6,553,600
  ushort_t* feat   = (ushort_t*)(ws + 6758400);    // 16384*400*2   = 13,107,200
  ushort_t* hh     = (ushort_t*)(ws + 19865600);   // 2*257*64*304*2 = 20,000,768  (was 19,988,480: overlapped logits!)
  float*    logits = (float*)   (ws + 39866368);   // 2*16384*20*4  = 2,621,440
  int*      cnt    = (int*)     (ws + 42487808);   // 32 ints
                                                   // total ~42.5 MB

  static const int LDS_W = 64*328*2 + 64*416*2 + 64*52*4;   // 108,544 B
  hipFuncSetAttribute((const void*)k_word2, hipFuncAttributeMaxDynamicSharedMemorySize, LDS_W);

  hipLaunchKernelGGL(k_init, dim3((HH_DWORDS + 32 + 255)/256), dim3(256), 0, stream,
                     (unsigned int*)hh, cnt);
  hipLaunchKernelGGL(k_ctab, dim3(200), dim3(256), 0, stream, cemb, cWih, cbih, cbhh, Ec);
  hipLaunchKernelGGL(k_char, dim3(256), dim3(256), 0, stream, Ec, cWhh, char_x, c_h);
  hipLaunchKernelGGL(k_feat, dim3(6400), dim3(256), 0, stream, word_x, wemb, c_h, feat);
  hipLaunchKernelGGL(k_word2, dim3(2*NW_), dim3(512), LDS_W, stream,
                     feat, hh, fWih, fWhh, fbih, fbhh, bWih, bWhh, bbih, bbhh, word_x, cnt);
  hipLaunchKernelGGL(k_logits, dim3(NSEQ/16, 2), dim3(320), 0, stream, hh, outW, logits);
  hipLaunchKernelGGL(k_crf, dim3(64), dim3(64), 0, stream, logits, outb, trans, word_x, y, out);
}

// Round 5
// 3628.512 us; speedup vs baseline: 2.8712x; 1.4485x over previous
//
#include <hip/hip_runtime.h>

#define B_ 64
#define T_ 256
#define LC_ 16
#define CV_ 128
#define CE_ 100
#define WE_ 300
#define CH_ 100
#define WH_ 300
#define NTAG 20
#define START_ 18
#define STOP_ 19
#define NEG_ -10000.0f
#define NSEQ (B_*T_)          // 16384
#define GW (4*WH_)            // 1200
#define KF (WE_+CH_)          // 400
#define NW_ 25                // workgroups per direction in k_word2
#define UH_ 12                // hidden units per workgroup (25*12=300)

typedef unsigned short ushort_t;
typedef __attribute__((ext_vector_type(8))) short bf16x8;
typedef __attribute__((ext_vector_type(4))) float f32x4;
union BF8 { bf16x8 v; ushort_t u[8]; };

__device__ inline float bf2f(ushort_t u){ return __uint_as_float(((unsigned int)u)<<16); }
__device__ inline ushort_t f2bf(float f){
  unsigned int x = __float_as_uint(f);
  unsigned int r = (x + 0x7fffu + ((x>>16)&1u)) >> 16;
  return (ushort_t)r;
}
__device__ inline float sigm(float x){ return 1.f/(1.f+__expf(-x)); }
__device__ inline float ftanh(float x){
  float ax = fabsf(x);
  float e = __expf(-2.f*ax);
  float t = (1.f-e)/(1.f+e);
  return copysignf(t, x);
}

// ---------- 0. init: zero h-history (incl. padding cols) and sync counters
#define HH_SHORTS (2*257*64*304)   // 10,000,384 shorts = 20,000,768 bytes
#define HH_DWORDS (HH_SHORTS/2)
__global__ __launch_bounds__(256) void k_init(unsigned int* __restrict__ hh, int* __restrict__ cnt){
  size_t idx = (size_t)blockIdx.x*256 + threadIdx.x;
  if (idx < HH_DWORDS) hh[idx] = 0u;
  else if (idx < HH_DWORDS + 32) cnt[idx - HH_DWORDS] = 0;
}

// ---------- 1. char gate table: Ec[r][c] = char_emb[c] . cW_ih[r] + cb_ih[r]+cb_hh[r]
__global__ __launch_bounds__(256) void k_ctab(const float* __restrict__ cemb,
    const float* __restrict__ cWih, const float* __restrict__ cbih,
    const float* __restrict__ cbhh, float* __restrict__ Ec){
  int idx = blockIdx.x*256 + threadIdx.x;      // 51200 = 400*128
  int r = idx >> 7, c = idx & 127;
  float a = cbih[r] + cbhh[r];
  for (int k=0;k<CE_;++k) a += cemb[c*CE_+k]*cWih[r*CE_+k];
  Ec[r*128 + c] = a;
}

// ---------- 2. char LSTM: 64 seqs per WG, wave w owns units [25w,25w+25)
__global__ __launch_bounds__(256) void k_char(const float* __restrict__ Ec,
    const float* __restrict__ Whh, const int* __restrict__ char_x,
    float* __restrict__ c_h){
  __shared__ __attribute__((aligned(16))) float h_s[64][108];
  __shared__ __attribute__((aligned(16))) float c_s[64][108];
  int tid = threadIdx.x;
  int lane = tid & 63;
  int w = __builtin_amdgcn_readfirstlane(tid >> 6);
  int seq = blockIdx.x*64 + lane;
  float* hs = &h_s[0][0]; float* cs = &c_s[0][0];
  for (int i=tid; i<64*108; i+=256){ hs[i]=0.f; cs[i]=0.f; }
  __syncthreads();
  const int* cx = char_x + (size_t)seq*LC_;
  #pragma unroll 1
  for (int t=0; t<LC_; ++t){
    float hr[100];
    #pragma unroll
    for (int q=0;q<25;++q){
      float4 v = *(const float4*)&h_s[lane][q*4];
      hr[q*4]=v.x; hr[q*4+1]=v.y; hr[q*4+2]=v.z; hr[q*4+3]=v.w;
    }
    int ch = cx[t];
    __syncthreads();
    #pragma unroll 1
    for (int jj=0;jj<25;++jj){
      int j = w*25 + jj;
      float ai = Ec[(j       )*128 + ch];
      float af = Ec[(100 + j )*128 + ch];
      float ag = Ec[(200 + j )*128 + ch];
      float ao = Ec[(300 + j )*128 + ch];
      const float* wi = Whh + (size_t)(j      )*CE_;
      const float* wf = Whh + (size_t)(100 + j)*CE_;
      const float* wg = Whh + (size_t)(200 + j)*CE_;
      const float* wo = Whh + (size_t)(300 + j)*CE_;
      #pragma unroll
      for (int k=0;k<100;++k){
        float hk = hr[k];
        ai += wi[k]*hk; af += wf[k]*hk; ag += wg[k]*hk; ao += wo[k]*hk;
      }
      float I = sigm(ai), F = sigm(af), G = ftanh(ag), O = sigm(ao);
      float cn = F*c_s[lane][j] + I*G;
      float hn = O*ftanh(cn);
      if (ch > 0){ c_s[lane][j] = cn; h_s[lane][j] = hn; }
    }
    __syncthreads();
  }
  #pragma unroll 1
  for (int jj=0;jj<25;++jj){ int j=w*25+jj; c_h[(size_t)seq*CH_+j] = h_s[lane][j]; }
}

// ---------- 3. feat builder: feat[t][b][0..400) bf16 = concat(wemb[word_x], c_h)
__global__ __launch_bounds__(256) void k_feat(const int* __restrict__ word_x,
    const float* __restrict__ wemb, const float* __restrict__ c_h,
    ushort_t* __restrict__ feat){
  int gid = blockIdx.x*256 + threadIdx.x;      // 16384*100 groups of 4 cols
  int rf = gid / 100;                          // rf = t*64 + b
  int j4 = gid - rf*100;
  int k = 4*j4;
  int t = rf >> 6, b = rf & 63;
  int seq = b*T_ + t;
  float4 v;
  if (k < WE_){ int wid = word_x[seq]; v = *(const float4*)&wemb[(size_t)wid*WE_ + k]; }
  else        { v = *(const float4*)&c_h[(size_t)seq*CH_ + (k - WE_)]; }
  ushort4 u; u.x=f2bf(v.x); u.y=f2bf(v.y); u.z=f2bf(v.z); u.w=f2bf(v.w);
  *(ushort4*)&feat[(size_t)rf*KF + k] = u;
}

// ---------- 4. word LSTM: distributed recurrence, persistent weights in VGPRs,
//              MFMA gates, fence-free sc1 handshake across NW_ WGs per direction.
__global__ __launch_bounds__(512, 2) void k_word2(
    const ushort_t* __restrict__ feat, ushort_t* __restrict__ hh,
    const float* __restrict__ fWih, const float* __restrict__ fWhh,
    const float* __restrict__ fbih, const float* __restrict__ fbhh,
    const float* __restrict__ bWih, const float* __restrict__ bWhh,
    const float* __restrict__ bbih, const float* __restrict__ bbhh,
    const int* __restrict__ word_x, int* __restrict__ cnt){
  extern __shared__ char smem[];
  ushort_t* h_s = (ushort_t*)smem;                         // [64][328] bf16 = 41984 B
  ushort_t* f_s = (ushort_t*)(smem + 64*328*2);            // [64][416] bf16 = 53248 B
  float*    g_s = (float*)   (smem + 64*328*2 + 64*416*2); // [64][52] f32   = 13312 B
  const int tid  = threadIdx.x;
  const int lane = tid & 63;
  const int w    = tid >> 6;         // 8 waves
  const int dir  = blockIdx.x & 1;
  const int g    = blockIdx.x >> 1;  // 0..24
  const int u0   = g * UH_;
  const int tm   = w & 3;            // m-tile (batch 16-row group)
  const int grp  = w >> 2;           // 0: n-tiles {0,1}; 1: n-tile {2}
  const bool two = (grp == 0);
  const int tnb  = grp ? 2 : 0;
  const float* Wih = dir ? bWih : fWih;
  const float* Whh = dir ? bWhh : fWhh;
  const float* bi  = dir ? bbih : fbih;
  const float* bh  = dir ? bbhh : fbhh;
  int* mycnt = cnt + dir*16;

  // ---- persistent B fragments (W_ih: 13 k-slabs; W_hh: 10 k-slabs)
  bf16x8 B2[2][13], B1[2][10];
  {
    const int kb = 8*(lane >> 4);
    #pragma unroll
    for (int ti=0; ti<2; ++ti){
      if (ti == 0 || two){
        int nl = 16*(tnb+ti) + (lane & 15);
        int r  = (nl & 3)*WH_ + u0 + (nl >> 2);   // gate q*300 + unit
        #pragma unroll
        for (int kk=0; kk<13; ++kk){
          BF8 tmp;
          #pragma unroll
          for (int j=0; j<8; ++j){
            int k = 32*kk + kb + j;
            tmp.u[j] = (k < KF) ? f2bf(Wih[(size_t)r*KF + k]) : (ushort_t)0;
          }
          B2[ti][kk] = tmp.v;
        }
        #pragma unroll
        for (int kk=0; kk<10; ++kk){
          BF8 tmp;
          #pragma unroll
          for (int j=0; j<8; ++j){
            int k = 32*kk + kb + j;
            tmp.u[j] = (k < WH_) ? f2bf(Whh[(size_t)r*WH_ + k]) : (ushort_t)0;
          }
          B1[ti][kk] = tmp.v;
        }
      }
    }
  }
  // ---- zero LDS K-padding (h cols 304..327, feat cols 400..415)
  for (int idx=tid; idx<64*24; idx+=512){ int m = idx/24; h_s[m*328 + 304 + (idx - m*24)] = 0; }
  for (int idx=tid; idx<64*16; idx+=512){ f_s[(idx>>4)*416 + 400 + (idx & 15)] = 0; }

  // ---- update threads: tid<384: m_u = tid&63, up = tid>>6 (units u0+2up, u0+2up+1)
  const int m_u = tid & 63;
  const int up  = tid >> 6;          // 0..5 for update threads
  float4 bias_a = {0,0,0,0}, bias_b = {0,0,0,0};
  if (tid < 384){
    int u = u0 + 2*up;
    bias_a.x = bi[0*WH_+u] + bh[0*WH_+u];
    bias_a.y = bi[1*WH_+u] + bh[1*WH_+u];
    bias_a.z = bi[2*WH_+u] + bh[2*WH_+u];
    bias_a.w = bi[3*WH_+u] + bh[3*WH_+u];
    bias_b.x = bi[0*WH_+u+1] + bh[0*WH_+u+1];
    bias_b.y = bi[1*WH_+u+1] + bh[1*WH_+u+1];
    bias_b.z = bi[2*WH_+u+1] + bh[2*WH_+u+1];
    bias_b.w = bi[3*WH_+u+1] + bh[3*WH_+u+1];
  }
  float c_a=0.f, h_a=0.f, c_b=0.f, h_b=0.f;
  const int arow_f = (16*tm + (lane&15))*416 + 8*(lane>>4);
  const int arow_h = (16*tm + (lane&15))*328 + 8*(lane>>4);
  unsigned* hhd = (unsigned*)hh;          // dword view (rows of 152 dwords)
  __syncthreads();

  #pragma unroll 1
  for (int s=0; s<T_; ++s){
    int t = dir ? (T_-1-s) : s;
    // -- wait until all WGs of this dir published h slot s (relaxed agent poll; no fence)
    if (s > 0 && tid == 0){
      int tgt = NW_*s;
      for (int it=0; it<4000000; ++it){
        if (__hip_atomic_load(mycnt, __ATOMIC_RELAXED, __HIP_MEMORY_SCOPE_AGENT) >= tgt) break;
        __builtin_amdgcn_s_sleep(1);
      }
    }
    __syncthreads();
    // -- stage h(s): 9728 dwords = 512 threads x 19, agent-scope (coherent-point) loads
    {
      const unsigned* hsrc = hhd + (size_t)(dir*257 + s)*64*152;
      unsigned* hdl = (unsigned*)h_s;
      unsigned v[19]; int mi[19], ji[19];
      #pragma unroll
      for (int i=0;i<19;++i){
        int idx = tid + 512*i;
        int m = idx/152, j = idx - m*152;
        mi[i]=m; ji[i]=j;
        v[i] = __hip_atomic_load(hsrc + m*152 + j, __ATOMIC_RELAXED, __HIP_MEMORY_SCOPE_AGENT);
      }
      #pragma unroll
      for (int i=0;i<19;++i) hdl[mi[i]*164 + ji[i]] = v[i];
    }
    // -- stage feat(t): 64 rows x 400 bf16 (read-only data, plain cached loads)
    {
      const ushort_t* fsrc = feat + (size_t)t*64*KF;
      for (int idx=tid; idx<3200; idx+=512){
        int m = idx/50, j = idx - m*50;
        uint4 v = *(const uint4*)(fsrc + m*KF + 8*j);
        *(uint4*)(f_s + m*416 + 8*j) = v;
      }
    }
    __syncthreads();
    // -- MFMA: gates(64 x 48-slice) = feat*Wih^T + h*Whh^T
    f32x4 acc0a = {0,0,0,0}, acc0b = {0,0,0,0}, acc1a = {0,0,0,0}, acc1b = {0,0,0,0};
    #pragma unroll
    for (int kk=0; kk<13; ++kk){
      bf16x8 a = *(const bf16x8*)(f_s + arow_f + 32*kk);
      if (kk & 1){
        acc0b = __builtin_amdgcn_mfma_f32_16x16x32_bf16(a, B2[0][kk], acc0b, 0,0,0);
        if (two) acc1b = __builtin_amdgcn_mfma_f32_16x16x32_bf16(a, B2[1][kk], acc1b, 0,0,0);
      } else {
        acc0a = __builtin_amdgcn_mfma_f32_16x16x32_bf16(a, B2[0][kk], acc0a, 0,0,0);
        if (two) acc1a = __builtin_amdgcn_mfma_f32_16x16x32_bf16(a, B2[1][kk], acc1a, 0,0,0);
      }
    }
    #pragma unroll
    for (int kk=0; kk<10; ++kk){
      bf16x8 a = *(const bf16x8*)(h_s + arow_h + 32*kk);
      if (kk & 1){
        acc0b = __builtin_amdgcn_mfma_f32_16x16x32_bf16(a, B1[0][kk], acc0b, 0,0,0);
        if (two) acc1b = __builtin_amdgcn_mfma_f32_16x16x32_bf16(a, B1[1][kk], acc1b, 0,0,0);
      } else {
        acc0a = __builtin_amdgcn_mfma_f32_16x16x32_bf16(a, B1[0][kk], acc0a, 0,0,0);
        if (two) acc1a = __builtin_amdgcn_mfma_f32_16x16x32_bf16(a, B1[1][kk], acc1a, 0,0,0);
      }
    }
    // -- write gate fragments to g_s (own region; prior readers synced last step)
    {
      int nb = 16*tnb + (lane & 15);
      int mr = 16*tm + 4*(lane >> 4);
      f32x4 s0 = acc0a + acc0b;
      #pragma unroll
      for (int r4=0; r4<4; ++r4) g_s[(mr+r4)*52 + nb] = s0[r4];
      if (two){
        f32x4 s1 = acc1a + acc1b;
        #pragma unroll
        for (int r4=0; r4<4; ++r4) g_s[(mr+r4)*52 + nb + 16] = s1[r4];
      }
    }
    __syncthreads();
    // -- elementwise LSTM update + publish carried h (packed bf16 pair, sc1 store)
    if (tid < 384){
      int mt = word_x[m_u*T_ + t] > 0;
      float4 ga = *(const float4*)(g_s + m_u*52 + 8*up);
      float4 gb = *(const float4*)(g_s + m_u*52 + 8*up + 4);
      {
        float gi = sigm (ga.x + bias_a.x);
        float gf = sigm (ga.y + bias_a.y);
        float gg = ftanh(ga.z + bias_a.z);
        float go = sigm (ga.w + bias_a.w);
        float cn = gf*c_a + gi*gg;
        float hn = go*ftanh(cn);
        if (mt){ c_a = cn; h_a = hn; }
      }
      {
        float gi = sigm (gb.x + bias_b.x);
        float gf = sigm (gb.y + bias_b.y);
        float gg = ftanh(gb.z + bias_b.z);
        float go = sigm (gb.w + bias_b.w);
        float cn = gf*c_b + gi*gg;
        float hn = go*ftanh(cn);
        if (mt){ c_b = cn; h_b = hn; }
      }
      unsigned pack = (unsigned)f2bf(h_a) | ((unsigned)f2bf(h_b) << 16);
      unsigned* hdst = hhd + ((size_t)(dir*257 + s + 1)*64 + m_u)*152 + (u0>>1) + up;
      __hip_atomic_store(hdst, pack, __ATOMIC_RELAXED, __HIP_MEMORY_SCOPE_AGENT);
    }
    asm volatile("s_waitcnt vmcnt(0)" ::: "memory");
    __syncthreads();
    if (tid == 0) __hip_atomic_fetch_add(mycnt, 1, __ATOMIC_RELAXED, __HIP_MEMORY_SCOPE_AGENT);
  }
}

// ---------- 5. logits: logits[dir][seq][tag] = h_dir(t) . outW[tag][dir*300..]
__global__ __launch_bounds__(320) void k_logits(const ushort_t* __restrict__ hh,
    const float* __restrict__ outW, float* __restrict__ logits){
  __shared__ __attribute__((aligned(16))) ushort_t h_l[16][304];
  __shared__ __attribute__((aligned(16))) float    w_l[20][304];
  int tid = threadIdx.x;
  int dir = blockIdx.y;
  for (int idx=tid; idx<20*304; idx+=320){
    int tag = idx/304, k = idx - tag*304;
    w_l[tag][k] = (k < WH_) ? outW[(size_t)tag*(2*WH_) + dir*WH_ + k] : 0.f;
  }
  for (int idx=tid; idx<608; idx+=320){
    int m = idx/38, j = idx - m*38;
    int seq = blockIdx.x*16 + m;
    int b = seq >> 8, t = seq & 255;
    int slot = dir ? (T_ - t) : (t + 1);
    uint4 v = *(const uint4*)(hh + ((size_t)(dir*257 + slot)*64 + b)*304 + 8*j);
    *(uint4*)(&h_l[m][8*j]) = v;
  }
  __syncthreads();
  int sq = tid/20, tag = tid - sq*20;
  float acc = 0.f;
  #pragma unroll
  for (int jj=0; jj<76; ++jj){
    ushort_t h0 = h_l[sq][4*jj+0], h1 = h_l[sq][4*jj+1];
    ushort_t h2 = h_l[sq][4*jj+2], h3 = h_l[sq][4*jj+3];
    float4 wv = *(const float4*)&w_l[tag][4*jj];
    acc += bf2f(h0)*wv.x + bf2f(h1)*wv.y + bf2f(h2)*wv.z + bf2f(h3)*wv.w;
  }
  int seq = blockIdx.x*16 + sq;
  logits[((size_t)dir*NSEQ + seq)*NTAG + tag] = acc;
}

// ---------- 6. CRF forward + gold score (one wave per batch element)
__global__ __launch_bounds__(64) void k_crf(const float* __restrict__ logits,
    const float* __restrict__ out_b, const float* __restrict__ tr,
    const int* __restrict__ word_x, const int* __restrict__ y,
    float* __restrict__ out){
  __shared__ float tr_s[NTAG][21];
  __shared__ float al[NTAG];
  __shared__ float tmp[NTAG];
  int b = blockIdx.x, lane = threadIdx.x;
  for (int idx=lane; idx<NTAG*NTAG; idx+=64) tr_s[idx/NTAG][idx%NTAG] = tr[idx];
  if (lane < NTAG) al[lane] = (lane == START_) ? 0.f : NEG_;
  __syncthreads();
  const float* lf = logits + (size_t)b*T_*NTAG;
  const float* lb = logits + (size_t)NSEQ*NTAG + (size_t)b*T_*NTAG;
  #pragma unroll 1
  for (int t=0; t<T_; ++t){
    float anew = 0.f;
    int m_t = word_x[b*T_ + t] > 0;
    if (lane < NTAG){
      float hv = lf[t*NTAG + lane] + lb[t*NTAG + lane] + out_b[lane];
      hv = fminf(fmaxf(hv, -1e6f), 1e6f);
      float mx = -3.4e38f;
      #pragma unroll
      for (int j=0;j<NTAG;++j) mx = fmaxf(mx, al[j] + tr_s[lane][j]);
      float ss = 0.f;
      #pragma unroll
      for (int j=0;j<NTAG;++j) ss += __expf(al[j] + tr_s[lane][j] - mx);
      anew = __logf(ss) + mx + hv;
      if (!m_t) anew = al[lane];
    }
    __syncthreads();
    if (lane < NTAG) al[lane] = anew;
    __syncthreads();
  }
  if (lane < NTAG) tmp[lane] = al[lane] + tr_s[STOP_][lane];
  __syncthreads();
  float sc = 0.f; int cnt = 0;
  #pragma unroll 1
  for (int q=0;q<4;++q){
    int t = lane + 64*q;
    if (word_x[b*T_ + t] > 0){
      int yt = y[b*T_ + t];
      int yp = (t == 0) ? START_ : y[b*T_ + t - 1];
      float ev = lf[t*NTAG + yt] + lb[t*NTAG + yt] + out_b[yt];
      ev = fminf(fmaxf(ev, -1e6f), 1e6f);
      sc += ev + tr_s[yt][yp];
      cnt++;
    }
  }
  for (int off=32; off; off>>=1){
    sc += __shfl_down(sc, off);
    cnt += __shfl_down(cnt, off);
  }
  if (lane == 0){
    float mx = -3.4e38f;
    for (int j=0;j<NTAG;++j) mx = fmaxf(mx, tmp[j]);
    float ss = 0.f;
    for (int j=0;j<NTAG;++j) ss += __expf(tmp[j] - mx);
    float Z = __logf(ss) + mx;
    int last = y[b*T_ + cnt - 1];
    sc += tr_s[STOP_][last];
    out[b] = Z - sc;
  }
}

extern "C" void kernel_launch(void* const* d_in, const int* in_sizes, int n_in,
                              void* d_out, int out_size, void* d_ws, size_t ws_size,
                              hipStream_t stream) {
  (void)in_sizes; (void)n_in; (void)out_size; (void)ws_size;
  const int*   word_x  = (const int*)  d_in[0];
  const int*   char_x  = (const int*)  d_in[1];
  const int*   y       = (const int*)  d_in[2];
  const float* wemb    = (const float*)d_in[3];
  const float* cemb    = (const float*)d_in[4];
  const float* cWih    = (const float*)d_in[5];
  const float* cWhh    = (const float*)d_in[6];
  const float* cbih    = (const float*)d_in[7];
  const float* cbhh    = (const float*)d_in[8];
  const float* fWih    = (const float*)d_in[9];
  const float* fWhh    = (const float*)d_in[10];
  const float* fbih    = (const float*)d_in[11];
  const float* fbhh    = (const float*)d_in[12];
  const float* bWih    = (const float*)d_in[13];
  const float* bWhh    = (const float*)d_in[14];
  const float* bbih    = (const float*)d_in[15];
  const float* bbhh    = (const float*)d_in[16];
  const float* outW    = (const float*)d_in[17];
  const float* outb    = (const float*)d_in[18];
  const float* trans   = (const float*)d_in[19];
  float* out = (float*)d_out;

  char* ws = (char*)d_ws;
  // layout (bytes, 16-aligned):
  float*    Ec     = (float*)   (ws + 0);          //   204,800
  float*    c_h    = (float*)   (ws + 204800);     // 6,553,600
  ushort_t* feat   = (ushort_t*)(ws + 6758400);    // 16384*400*2   = 13,107,200
  ushort_t* hh     = (ushort_t*)(ws + 19865600);   // 2*257*64*304*2 = 20,000,768
  float*    logits = (float*)   (ws + 39866368);   // 2*16384*20*4  = 2,621,440
  int*      cnt    = (int*)     (ws + 42487808);   // 32 ints
                                                   // total ~42.5 MB

  static const int LDS_W = 64*328*2 + 64*416*2 + 64*52*4;   // 108,544 B
  hipFuncSetAttribute((const void*)k_word2, hipFuncAttributeMaxDynamicSharedMemorySize, LDS_W);

  hipLaunchKernelGGL(k_init, dim3((HH_DWORDS + 32 + 255)/256), dim3(256), 0, stream,
                     (unsigned int*)hh, cnt);
  hipLaunchKernelGGL(k_ctab, dim3(200), dim3(256), 0, stream, cemb, cWih, cbih, cbhh, Ec);
  hipLaunchKernelGGL(k_char, dim3(256), dim3(256), 0, stream, Ec, cWhh, char_x, c_h);
  hipLaunchKernelGGL(k_feat, dim3(6400), dim3(256), 0, stream, word_x, wemb, c_h, feat);
  hipLaunchKernelGGL(k_word2, dim3(2*NW_), dim3(512), LDS_W, stream,
                     feat, hh, fWih, fWhh, fbih, fbhh, bWih, bWhh, bbih, bbhh, word_x, cnt);
  hipLaunchKernelGGL(k_logits, dim3(NSEQ/16, 2), dim3(320), 0, stream, hh, outW, logits);
  hipLaunchKernelGGL(k_crf, dim3(64), dim3(64), 0, stream, logits, outb, trans, word_x, y, out);
}

// Round 6
// 3263.541 us; speedup vs baseline: 3.1923x; 1.1118x over previous
//
#include <hip/hip_runtime.h>

#define B_ 64
#define T_ 256
#define LC_ 16
#define CV_ 128
#define CE_ 100
#define WE_ 300
#define CH_ 100
#define WH_ 300
#define NTAG 20
#define START_ 18
#define STOP_ 19
#define NEG_ -10000.0f
#define NSEQ (B_*T_)          // 16384
#define GW (4*WH_)            // 1200
#define KF (WE_+CH_)          // 400
#define NW_ 25                // workgroups per direction in k_word2
#define UH_ 12                // hidden units per workgroup (25*12=300)
#define SLOT_DW 9600          // 25*64*6 dwords per slot
#define DIR_DW (257*SLOT_DW)  // dwords per direction

typedef unsigned short ushort_t;
typedef unsigned long long ull_t;
typedef __attribute__((ext_vector_type(8))) short bf16x8;
typedef __attribute__((ext_vector_type(4))) float f32x4;
union BF8 { bf16x8 v; ushort_t u[8]; };

__device__ inline float bf2f(ushort_t u){ return __uint_as_float(((unsigned int)u)<<16); }
__device__ inline ushort_t f2bf(float f){
  unsigned int x = __float_as_uint(f);
  unsigned int r = (x + 0x7fffu + ((x>>16)&1u)) >> 16;
  return (ushort_t)r;
}
__device__ inline float sigm(float x){ return 1.f/(1.f+__expf(-x)); }
__device__ inline float ftanh(float x){
  float ax = fabsf(x);
  float e = __expf(-2.f*ax);
  float t = (1.f-e)/(1.f+e);
  return copysignf(t, x);
}

// ---------- 0. init: zero h slot 0 (both dirs) + flags
__global__ __launch_bounds__(256) void k_init(unsigned int* __restrict__ hh, int* __restrict__ flags){
  int idx = blockIdx.x*256 + threadIdx.x;
  if (idx < SLOT_DW) hh[idx] = 0u;
  else if (idx < 2*SLOT_DW) hh[DIR_DW + (idx - SLOT_DW)] = 0u;
  else if (idx < 2*SLOT_DW + 64) flags[idx - 2*SLOT_DW] = 0;
}

// ---------- 1. char gate table: Ec[r][c] = char_emb[c] . cW_ih[r] + cb_ih[r]+cb_hh[r]
__global__ __launch_bounds__(256) void k_ctab(const float* __restrict__ cemb,
    const float* __restrict__ cWih, const float* __restrict__ cbih,
    const float* __restrict__ cbhh, float* __restrict__ Ec){
  int idx = blockIdx.x*256 + threadIdx.x;      // 51200 = 400*128
  int r = idx >> 7, c = idx & 127;
  float a = cbih[r] + cbhh[r];
  for (int k=0;k<CE_;++k) a += cemb[c*CE_+k]*cWih[r*CE_+k];
  Ec[r*128 + c] = a;
}

// ---------- 2. char LSTM: 64 seqs per WG, wave w owns units [25w,25w+25)
__global__ __launch_bounds__(256) void k_char(const float* __restrict__ Ec,
    const float* __restrict__ Whh, const int* __restrict__ char_x,
    float* __restrict__ c_h){
  __shared__ __attribute__((aligned(16))) float h_s[64][108];
  __shared__ __attribute__((aligned(16))) float c_s[64][108];
  int tid = threadIdx.x;
  int lane = tid & 63;
  int w = __builtin_amdgcn_readfirstlane(tid >> 6);
  int seq = blockIdx.x*64 + lane;
  float* hs = &h_s[0][0]; float* cs = &c_s[0][0];
  for (int i=tid; i<64*108; i+=256){ hs[i]=0.f; cs[i]=0.f; }
  __syncthreads();
  const int* cx = char_x + (size_t)seq*LC_;
  #pragma unroll 1
  for (int t=0; t<LC_; ++t){
    float hr[100];
    #pragma unroll
    for (int q=0;q<25;++q){
      float4 v = *(const float4*)&h_s[lane][q*4];
      hr[q*4]=v.x; hr[q*4+1]=v.y; hr[q*4+2]=v.z; hr[q*4+3]=v.w;
    }
    int ch = cx[t];
    __syncthreads();
    #pragma unroll 1
    for (int jj=0;jj<25;++jj){
      int j = w*25 + jj;
      float ai = Ec[(j       )*128 + ch];
      float af = Ec[(100 + j )*128 + ch];
      float ag = Ec[(200 + j )*128 + ch];
      float ao = Ec[(300 + j )*128 + ch];
      const float* wi = Whh + (size_t)(j      )*CE_;
      const float* wf = Whh + (size_t)(100 + j)*CE_;
      const float* wg = Whh + (size_t)(200 + j)*CE_;
      const float* wo = Whh + (size_t)(300 + j)*CE_;
      #pragma unroll
      for (int k=0;k<100;++k){
        float hk = hr[k];
        ai += wi[k]*hk; af += wf[k]*hk; ag += wg[k]*hk; ao += wo[k]*hk;
      }
      float I = sigm(ai), F = sigm(af), G = ftanh(ag), O = sigm(ao);
      float cn = F*c_s[lane][j] + I*G;
      float hn = O*ftanh(cn);
      if (ch > 0){ c_s[lane][j] = cn; h_s[lane][j] = hn; }
    }
    __syncthreads();
  }
  #pragma unroll 1
  for (int jj=0;jj<25;++jj){ int j=w*25+jj; c_h[(size_t)seq*CH_+j] = h_s[lane][j]; }
}

// ---------- 3. feat builder: feat[t][b][0..400) bf16 = concat(wemb[word_x], c_h)
__global__ __launch_bounds__(256) void k_feat(const int* __restrict__ word_x,
    const float* __restrict__ wemb, const float* __restrict__ c_h,
    ushort_t* __restrict__ feat){
  int gid = blockIdx.x*256 + threadIdx.x;      // 16384*100 groups of 4 cols
  int rf = gid / 100;                          // rf = t*64 + b
  int j4 = gid - rf*100;
  int k = 4*j4;
  int t = rf >> 6, b = rf & 63;
  int seq = b*T_ + t;
  float4 v;
  if (k < WE_){ int wid = word_x[seq]; v = *(const float4*)&wemb[(size_t)wid*WE_ + k]; }
  else        { v = *(const float4*)&c_h[(size_t)seq*CH_ + (k - WE_)]; }
  ushort4 u; u.x=f2bf(v.x); u.y=f2bf(v.y); u.z=f2bf(v.z); u.w=f2bf(v.w);
  *(ushort4*)&feat[(size_t)rf*KF + k] = u;
}

// ---------- 4. word LSTM: distributed recurrence, persistent weights in VGPRs,
//              MFMA gates, per-WG flag handshake (no RMW, no fences).
__global__ __launch_bounds__(512, 2) void k_word2(
    const ushort_t* __restrict__ feat, unsigned int* __restrict__ hhd,
    const float* __restrict__ fWih, const float* __restrict__ fWhh,
    const float* __restrict__ fbih, const float* __restrict__ fbhh,
    const float* __restrict__ bWih, const float* __restrict__ bWhh,
    const float* __restrict__ bbih, const float* __restrict__ bbhh,
    const int* __restrict__ word_x, int* __restrict__ flags){
  extern __shared__ char smem[];
  ushort_t* h_s    = (ushort_t*)smem;                          // [64][328] bf16 = 41984 B
  ushort_t* f_s    = (ushort_t*)(smem + 64*328*2);             // [64][416] bf16 = 53248 B
  float*    g_s    = (float*)   (smem + 64*328*2 + 64*416*2);  // [64][52] f32   = 13312 B
  unsigned* mask_s = (unsigned*)(smem + 64*328*2 + 64*416*2 + 64*52*4); // [64][8] = 2048 B
  const int tid  = threadIdx.x;
  const int lane = tid & 63;
  const int w    = tid >> 6;         // 8 waves
  const int dir  = blockIdx.x & 1;
  const int g    = blockIdx.x >> 1;  // 0..24
  const int u0   = g * UH_;
  const int tm   = w & 3;            // m-tile (batch 16-row group)
  const int grp  = w >> 2;           // 0: n-tiles {0,1}; 1: n-tile {2}
  const bool two = (grp == 0);
  const int tnb  = grp ? 2 : 0;
  const float* Wih = dir ? bWih : fWih;
  const float* Whh = dir ? bWhh : fWhh;
  const float* bi  = dir ? bbih : fbih;
  const float* bh  = dir ? bbhh : fbhh;
  int* myflags = flags + dir*32;

  // ---- persistent B fragments (W_ih: 13 k-slabs; W_hh: 10 k-slabs)
  bf16x8 B2[2][13], B1[2][10];
  {
    const int kb = 8*(lane >> 4);
    #pragma unroll
    for (int ti=0; ti<2; ++ti){
      if (ti == 0 || two){
        int nl = 16*(tnb+ti) + (lane & 15);
        int r  = (nl & 3)*WH_ + u0 + (nl >> 2);   // gate q*300 + unit
        #pragma unroll
        for (int kk=0; kk<13; ++kk){
          BF8 tmp;
          #pragma unroll
          for (int j=0; j<8; ++j){
            int k = 32*kk + kb + j;
            tmp.u[j] = (k < KF) ? f2bf(Wih[(size_t)r*KF + k]) : (ushort_t)0;
          }
          B2[ti][kk] = tmp.v;
        }
        #pragma unroll
        for (int kk=0; kk<10; ++kk){
          BF8 tmp;
          #pragma unroll
          for (int j=0; j<8; ++j){
            int k = 32*kk + kb + j;
            tmp.u[j] = (k < WH_) ? f2bf(Whh[(size_t)r*WH_ + k]) : (ushort_t)0;
          }
          B1[ti][kk] = tmp.v;
        }
      }
    }
  }
  unsigned* hdl = (unsigned*)h_s;
  // ---- zero LDS K-padding: h_s dword cols 150..163, f_s shorts 400..415
  for (int idx=tid; idx<64*14; idx+=512){ int m = idx/14; hdl[m*164 + 150 + (idx - m*14)] = 0u; }
  for (int idx=tid; idx<64*16; idx+=512){ f_s[(idx>>4)*416 + 400 + (idx & 15)] = 0; }
  // ---- build word-mask bitmap: mask_s[b][t>>5] bit (t&31)
  if (tid < 512){
    int row = tid >> 3, dw = tid & 7;
    const int* wp = word_x + row*T_ + dw*32;
    unsigned bits = 0u;
    #pragma unroll
    for (int j4=0; j4<8; ++j4){
      int4 v = *(const int4*)(wp + 4*j4);
      bits |= (v.x>0 ? 1u:0u) << (4*j4);
      bits |= (v.y>0 ? 1u:0u) << (4*j4+1);
      bits |= (v.z>0 ? 1u:0u) << (4*j4+2);
      bits |= (v.w>0 ? 1u:0u) << (4*j4+3);
    }
    mask_s[row*8 + dw] = bits;
  }

  // ---- update threads: tid<384: m_u = tid&63, up = tid>>6 (units u0+2up, u0+2up+1)
  const int m_u = tid & 63;
  const int up  = tid >> 6;          // 0..5 for update threads
  float4 bias_a = {0,0,0,0}, bias_b = {0,0,0,0};
  if (tid < 384){
    int u = u0 + 2*up;
    bias_a.x = bi[0*WH_+u] + bh[0*WH_+u];
    bias_a.y = bi[1*WH_+u] + bh[1*WH_+u];
    bias_a.z = bi[2*WH_+u] + bh[2*WH_+u];
    bias_a.w = bi[3*WH_+u] + bh[3*WH_+u];
    bias_b.x = bi[0*WH_+u+1] + bh[0*WH_+u+1];
    bias_b.y = bi[1*WH_+u+1] + bh[1*WH_+u+1];
    bias_b.z = bi[2*WH_+u+1] + bh[2*WH_+u+1];
    bias_b.w = bi[3*WH_+u+1] + bh[3*WH_+u+1];
  }
  float c_a=0.f, h_a=0.f, c_b=0.f, h_b=0.f;
  const int arow_f = (16*tm + (lane&15))*416 + 8*(lane>>4);
  const int arow_h = (16*tm + (lane&15))*328 + 8*(lane>>4);
  __syncthreads();

  #pragma unroll 1
  for (int s=0; s<T_; ++s){
    int t = dir ? (T_-1-s) : s;
    // -- stage feat(t) first: latency hides under the poll
    {
      const ushort_t* fsrc = feat + (size_t)t*64*KF;
      for (int idx=tid; idx<3200; idx+=512){
        int m = idx/50, j = idx - m*50;
        uint4 v = *(const uint4*)(fsrc + m*KF + 8*j);
        *(uint4*)(f_s + m*416 + 8*j) = v;
      }
    }
    // -- wait until all WGs of this dir published slot s (parallel flag poll, no RMW)
    if (w == 0 && s > 0){
      bool act = lane < NW_;
      for (int it=0; it<2000000; ++it){
        int f = act ? __hip_atomic_load(myflags + lane, __ATOMIC_RELAXED, __HIP_MEMORY_SCOPE_AGENT)
                    : 0x7fffffff;
        if (__all(f >= s)) break;
        __builtin_amdgcn_s_sleep(1);
      }
    }
    __syncthreads();
    // -- stage h(s): 4800 contiguous qwords, agent-scope loads, chunked layout
    {
      const ull_t* hsrc = (const ull_t*)(hhd + (size_t)(dir*257 + s)*SLOT_DW);
      ull_t v[10]; int di[10];
      #pragma unroll
      for (int i=0;i<10;++i){
        int idx = tid + 512*i;
        if (i < 9 || idx < 4800){
          int gc = idx / 192;
          int r  = idx - gc*192;
          int b  = r/3, q = r - b*3;
          di[i] = b*164 + gc*6 + 2*q;
          v[i] = __hip_atomic_load(hsrc + idx, __ATOMIC_RELAXED, __HIP_MEMORY_SCOPE_AGENT);
        }
      }
      #pragma unroll
      for (int i=0;i<10;++i){
        int idx = tid + 512*i;
        if (i < 9 || idx < 4800) *(ull_t*)(hdl + di[i]) = v[i];
      }
    }
    __syncthreads();
    // -- MFMA: gates(64 x 48-slice) = feat*Wih^T + h*Whh^T
    f32x4 acc0a = {0,0,0,0}, acc0b = {0,0,0,0}, acc1a = {0,0,0,0}, acc1b = {0,0,0,0};
    #pragma unroll
    for (int kk=0; kk<13; ++kk){
      bf16x8 a = *(const bf16x8*)(f_s + arow_f + 32*kk);
      if (kk & 1){
        acc0b = __builtin_amdgcn_mfma_f32_16x16x32_bf16(a, B2[0][kk], acc0b, 0,0,0);
        if (two) acc1b = __builtin_amdgcn_mfma_f32_16x16x32_bf16(a, B2[1][kk], acc1b, 0,0,0);
      } else {
        acc0a = __builtin_amdgcn_mfma_f32_16x16x32_bf16(a, B2[0][kk], acc0a, 0,0,0);
        if (two) acc1a = __builtin_amdgcn_mfma_f32_16x16x32_bf16(a, B2[1][kk], acc1a, 0,0,0);
      }
    }
    #pragma unroll
    for (int kk=0; kk<10; ++kk){
      bf16x8 a = *(const bf16x8*)(h_s + arow_h + 32*kk);
      if (kk & 1){
        acc0b = __builtin_amdgcn_mfma_f32_16x16x32_bf16(a, B1[0][kk], acc0b, 0,0,0);
        if (two) acc1b = __builtin_amdgcn_mfma_f32_16x16x32_bf16(a, B1[1][kk], acc1b, 0,0,0);
      } else {
        acc0a = __builtin_amdgcn_mfma_f32_16x16x32_bf16(a, B1[0][kk], acc0a, 0,0,0);
        if (two) acc1a = __builtin_amdgcn_mfma_f32_16x16x32_bf16(a, B1[1][kk], acc1a, 0,0,0);
      }
    }
    // -- write gate fragments to g_s
    {
      int nb = 16*tnb + (lane & 15);
      int mr = 16*tm + 4*(lane >> 4);
      f32x4 s0 = acc0a + acc0b;
      #pragma unroll
      for (int r4=0; r4<4; ++r4) g_s[(mr+r4)*52 + nb] = s0[r4];
      if (two){
        f32x4 s1 = acc1a + acc1b;
        #pragma unroll
        for (int r4=0; r4<4; ++r4) g_s[(mr+r4)*52 + nb + 16] = s1[r4];
      }
    }
    __syncthreads();
    // -- elementwise LSTM update + publish carried h (own contiguous chunk)
    if (tid < 384){
      int mt = (mask_s[m_u*8 + (t>>5)] >> (t&31)) & 1u;
      float4 ga = *(const float4*)(g_s + m_u*52 + 8*up);
      float4 gb = *(const float4*)(g_s + m_u*52 + 8*up + 4);
      {
        float gi = sigm (ga.x + bias_a.x);
        float gf = sigm (ga.y + bias_a.y);
        float gg = ftanh(ga.z + bias_a.z);
        float go = sigm (ga.w + bias_a.w);
        float cn = gf*c_a + gi*gg;
        float hn = go*ftanh(cn);
        if (mt){ c_a = cn; h_a = hn; }
      }
      {
        float gi = sigm (gb.x + bias_b.x);
        float gf = sigm (gb.y + bias_b.y);
        float gg = ftanh(gb.z + bias_b.z);
        float go = sigm (gb.w + bias_b.w);
        float cn = gf*c_b + gi*gg;
        float hn = go*ftanh(cn);
        if (mt){ c_b = cn; h_b = hn; }
      }
      unsigned pack = (unsigned)f2bf(h_a) | ((unsigned)f2bf(h_b) << 16);
      unsigned* hdst = hhd + (size_t)(dir*257 + s + 1)*SLOT_DW + (g*64 + m_u)*6 + up;
      __hip_atomic_store(hdst, pack, __ATOMIC_RELAXED, __HIP_MEMORY_SCOPE_AGENT);
    }
    asm volatile("s_waitcnt vmcnt(0)" ::: "memory");
    __syncthreads();   // all waves' stores drained
    if (tid == 0)
      __hip_atomic_store(myflags + g, s + 1, __ATOMIC_RELAXED, __HIP_MEMORY_SCOPE_AGENT);
  }
}

// ---------- 5. logits: logits[dir][seq][tag] = h_dir(t) . outW[tag][dir*300..]
__global__ __launch_bounds__(320) void k_logits(const unsigned int* __restrict__ hhd,
    const float* __restrict__ outW, float* __restrict__ logits){
  __shared__ __attribute__((aligned(16))) ushort_t h_l[16][304];
  __shared__ __attribute__((aligned(16))) float    w_l[20][304];
  int tid = threadIdx.x;
  int dir = blockIdx.y;
  for (int idx=tid; idx<20*304; idx+=320){
    int tag = idx/304, k = idx - tag*304;
    w_l[tag][k] = (k < WH_) ? outW[(size_t)tag*(2*WH_) + dir*WH_ + k] : 0.f;
  }
  unsigned* hld = (unsigned*)&h_l[0][0];
  for (int idx=tid; idx<2400; idx+=320){       // 16 rows x 150 dwords
    int m = idx/150, d = idx - m*150;
    int gc = d/6, q = d - gc*6;
    int seq = blockIdx.x*16 + m;
    int b = seq >> 8, t = seq & 255;
    int slot = dir ? (T_ - t) : (t + 1);
    hld[m*152 + d] = hhd[(size_t)(dir*257 + slot)*SLOT_DW + (gc*64 + b)*6 + q];
  }
  __syncthreads();
  int sq = tid/20, tag = tid - sq*20;
  float acc = 0.f;
  #pragma unroll
  for (int jj=0; jj<75; ++jj){
    ushort_t h0 = h_l[sq][4*jj+0], h1 = h_l[sq][4*jj+1];
    ushort_t h2 = h_l[sq][4*jj+2], h3 = h_l[sq][4*jj+3];
    float4 wv = *(const float4*)&w_l[tag][4*jj];
    acc += bf2f(h0)*wv.x + bf2f(h1)*wv.y + bf2f(h2)*wv.z + bf2f(h3)*wv.w;
  }
  int seq = blockIdx.x*16 + sq;
  logits[((size_t)dir*NSEQ + seq)*NTAG + tag] = acc;
}

// ---------- 6. CRF forward + gold score (one wave per batch element)
__global__ __launch_bounds__(64) void k_crf(const float* __restrict__ logits,
    const float* __restrict__ out_b, const float* __restrict__ tr,
    const int* __restrict__ word_x, const int* __restrict__ y,
    float* __restrict__ out){
  __shared__ float tr_s[NTAG][21];
  __shared__ float al[NTAG];
  __shared__ float tmp[NTAG];
  int b = blockIdx.x, lane = threadIdx.x;
  for (int idx=lane; idx<NTAG*NTAG; idx+=64) tr_s[idx/NTAG][idx%NTAG] = tr[idx];
  if (lane < NTAG) al[lane] = (lane == START_) ? 0.f : NEG_;
  __syncthreads();
  const float* lf = logits + (size_t)b*T_*NTAG;
  const float* lb = logits + (size_t)NSEQ*NTAG + (size_t)b*T_*NTAG;
  #pragma unroll 1
  for (int t=0; t<T_; ++t){
    float anew = 0.f;
    int m_t = word_x[b*T_ + t] > 0;
    if (lane < NTAG){
      float hv = lf[t*NTAG + lane] + lb[t*NTAG + lane] + out_b[lane];
      hv = fminf(fmaxf(hv, -1e6f), 1e6f);
      float mx = -3.4e38f;
      #pragma unroll
      for (int j=0;j<NTAG;++j) mx = fmaxf(mx, al[j] + tr_s[lane][j]);
      float ss = 0.f;
      #pragma unroll
      for (int j=0;j<NTAG;++j) ss += __expf(al[j] + tr_s[lane][j] - mx);
      anew = __logf(ss) + mx + hv;
      if (!m_t) anew = al[lane];
    }
    __syncthreads();
    if (lane < NTAG) al[lane] = anew;
    __syncthreads();
  }
  if (lane < NTAG) tmp[lane] = al[lane] + tr_s[STOP_][lane];
  __syncthreads();
  float sc = 0.f; int cnt = 0;
  #pragma unroll 1
  for (int q=0;q<4;++q){
    int t = lane + 64*q;
    if (word_x[b*T_ + t] > 0){
      int yt = y[b*T_ + t];
      int yp = (t == 0) ? START_ : y[b*T_ + t - 1];
      float ev = lf[t*NTAG + yt] + lb[t*NTAG + yt] + out_b[yt];
      ev = fminf(fmaxf(ev, -1e6f), 1e6f);
      sc += ev + tr_s[yt][yp];
      cnt++;
    }
  }
  for (int off=32; off; off>>=1){
    sc += __shfl_down(sc, off);
    cnt += __shfl_down(cnt, off);
  }
  if (lane == 0){
    float mx = -3.4e38f;
    for (int j=0;j<NTAG;++j) mx = fmaxf(mx, tmp[j]);
    float ss = 0.f;
    for (int j=0;j<NTAG;++j) ss += __expf(tmp[j] - mx);
    float Z = __logf(ss) + mx;
    int last = y[b*T_ + cnt - 1];
    sc += tr_s[STOP_][last];
    out[b] = Z - sc;
  }
}

extern "C" void kernel_launch(void* const* d_in, const int* in_sizes, int n_in,
                              void* d_out, int out_size, void* d_ws, size_t ws_size,
                              hipStream_t stream) {
  (void)in_sizes; (void)n_in; (void)out_size; (void)ws_size;
  const int*   word_x  = (const int*)  d_in[0];
  const int*   char_x  = (const int*)  d_in[1];
  const int*   y       = (const int*)  d_in[2];
  const float* wemb    = (const float*)d_in[3];
  const float* cemb    = (const float*)d_in[4];
  const float* cWih    = (const float*)d_in[5];
  const float* cWhh    = (const float*)d_in[6];
  const float* cbih    = (const float*)d_in[7];
  const float* cbhh    = (const float*)d_in[8];
  const float* fWih    = (const float*)d_in[9];
  const float* fWhh    = (const float*)d_in[10];
  const float* fbih    = (const float*)d_in[11];
  const float* fbhh    = (const float*)d_in[12];
  const float* bWih    = (const float*)d_in[13];
  const float* bWhh    = (const float*)d_in[14];
  const float* bbih    = (const float*)d_in[15];
  const float* bbhh    = (const float*)d_in[16];
  const float* outW    = (const float*)d_in[17];
  const float* outb    = (const float*)d_in[18];
  const float* trans   = (const float*)d_in[19];
  float* out = (float*)d_out;

  char* ws = (char*)d_ws;
  // layout (bytes, 256-aligned):
  float*        Ec     = (float*)       (ws + 0);          //   204,800
  float*        c_h    = (float*)       (ws + 204800);     // 6,553,600
  ushort_t*     feat   = (ushort_t*)    (ws + 6758400);    // 13,107,200
  unsigned int* hh     = (unsigned int*)(ws + 19865600);   // 2*257*9600*4 = 19,737,600
  int*          flags  = (int*)         (ws + 39603200);   // 64 ints = 256
  float*        logits = (float*)       (ws + 39603456);   // 2,621,440 -> end 42,224,896
  static const int LDS_W = 64*328*2 + 64*416*2 + 64*52*4 + 64*8*4;   // 110,592 B
  hipFuncSetAttribute((const void*)k_word2, hipFuncAttributeMaxDynamicSharedMemorySize, LDS_W);

  hipLaunchKernelGGL(k_init, dim3((2*SLOT_DW + 64 + 255)/256), dim3(256), 0, stream, hh, flags);
  hipLaunchKernelGGL(k_ctab, dim3(200), dim3(256), 0, stream, cemb, cWih, cbih, cbhh, Ec);
  hipLaunchKernelGGL(k_char, dim3(256), dim3(256), 0, stream, Ec, cWhh, char_x, c_h);
  hipLaunchKernelGGL(k_feat, dim3(6400), dim3(256), 0, stream, word_x, wemb, c_h, feat);
  hipLaunchKernelGGL(k_word2, dim3(2*NW_), dim3(512), LDS_W, stream,
                     feat, hh, fWih, fWhh, fbih, fbhh, bWih, bWhh, bbih, bbhh, word_x, flags);
  hipLaunchKernelGGL(k_logits, dim3(NSEQ/16, 2), dim3(320), 0, stream, hh, outW, logits);
  hipLaunchKernelGGL(k_crf, dim3(64), dim3(64), 0, stream, logits, outb, trans, word_x, y, out);
}